// Round 10
// baseline (517.379 us; speedup 1.0000x reference)
//
#include <hip/hip_runtime.h>
#include <hip/hip_bf16.h>
#include <math.h>

// L=1024, BT=64, D=768, HID=192, NH=4, hd=48, K=5, Hh=Ww=32, T=16, M=65536
//
//  cvt: weights -> bf16 (one launch). x stays fp32 (fc1 converts in-register).
//  1. xs0   = x @ fc1_w.T + b      (M x 192) bf16  [fc1: fp32-A reg-staged]
//  2. bottleneck fused: a=xs0@cvA.T; b=a@cvB.T; g=gelu(b+bB+xs0);
//     xs_sp[spatial]=g; ln_sp[spatial]=LN(g)   (BM=64, 80KB LDS, 2 blk/CU)
//  3. qkv   = ln_sp @ qkv_w.T + b  (M x 576) bf16  [full-K BM=64, 3 blk/CU]
//  4. natten -> o                  (M x 192) bf16  (LDS K/V halo only, 3 blk/CU)
//  5. y     = o @ proj_w.T + b + xs_sp             [full-K BM=64]
//  6. out   = scatter(y @ fc2_w.T + b + x) fp32 permuted, swapped-mfma [full-K]

typedef __attribute__((ext_vector_type(4))) float f32x4;
typedef __attribute__((ext_vector_type(8))) __bf16 bf16x8;
typedef const __attribute__((address_space(1))) void gv_t;
typedef __attribute__((address_space(3))) void lv_t;

__device__ __forceinline__ uint2 pack_bf16x4(float4 v) {
  union { unsigned short u[4]; uint2 d; } o;
  __hip_bfloat16 b0 = __float2bfloat16(v.x);
  __hip_bfloat16 b1 = __float2bfloat16(v.y);
  __hip_bfloat16 b2 = __float2bfloat16(v.z);
  __hip_bfloat16 b3 = __float2bfloat16(v.w);
  o.u[0] = *(unsigned short*)&b0; o.u[1] = *(unsigned short*)&b1;
  o.u[2] = *(unsigned short*)&b2; o.u[3] = *(unsigned short*)&b3;
  return o.d;
}

// ---------------- fc1: C(Mx192) = X(fp32, Mx768) @ W^T + bias, bf16 out ----
__global__ __launch_bounds__(512, 4) void fc1_kernel(
    const float* __restrict__ X, const __hip_bfloat16* __restrict__ W,
    const float* __restrict__ bias, __hip_bfloat16* __restrict__ C) {
  __shared__ __hip_bfloat16 Asm[2][128 * 64];   // 32 KB
  __shared__ __hip_bfloat16 Bsm[2][192 * 64];   // 48 KB

  const int tid = threadIdx.x;
  const int lane = tid & 63;
  const int wave = tid >> 6;
  const int lid = blockIdx.x;                   // 512 blocks
  const int bm0 = (((lid & 7) << 6) + (lid >> 3)) << 7;   // m-panel XCD swizzle
  const int wm0 = (wave >> 1) * 32;
  const int wn0 = (wave & 1) * 96;
  const int l15 = lane & 15;
  const int l7 = lane & 7;
  const int lg = lane >> 4;

  f32x4 acc[2][6] = {};
  float4 ar[4];

  auto stageB = [&](int buf, int k0) {
#pragma unroll
    for (int it = 0; it < 3; ++it) {
      int ci = tid + it * 512;                  // 0..1535
      int r = ci >> 3, c = ci & 7;
      int sc = c ^ (r & 7);
      const __hip_bfloat16* src = W + (size_t)r * 768 + k0 + sc * 8;
      __builtin_amdgcn_global_load_lds((gv_t*)src, (lv_t*)&Bsm[buf][ci * 8], 16, 0, 0);
    }
  };
  auto loadA = [&](int k0) {
#pragma unroll
    for (int q = 0; q < 2; ++q) {
      int ci = tid + q * 512;                   // 0..1023
      int r = ci >> 3, c = ci & 7;
      int sc = c ^ (r & 7);
      const float* src = X + (size_t)(bm0 + r) * 768 + k0 + sc * 8;
      ar[2 * q] = *(const float4*)src;
      ar[2 * q + 1] = *(const float4*)(src + 4);
    }
  };
  auto writeA = [&](int buf) {
#pragma unroll
    for (int q = 0; q < 2; ++q) {
      int ci = tid + q * 512;
      uint2 a = pack_bf16x4(ar[2 * q]);
      uint2 b = pack_bf16x4(ar[2 * q + 1]);
      uint4 w; w.x = a.x; w.y = a.y; w.z = b.x; w.w = b.y;
      *(uint4*)&Asm[buf][ci * 8] = w;
    }
  };

  stageB(0, 0);
  loadA(0);
  int cur = 0;
  for (int kt = 0; kt < 12; ++kt) {
    writeA(cur);
    __syncthreads();
    if (kt < 11) { stageB(cur ^ 1, (kt + 1) * 64); loadA((kt + 1) * 64); }
    const char* Ab = (const char*)&Asm[cur][0];
    const char* Bb = (const char*)&Bsm[cur][0];
#pragma unroll
    for (int kk = 0; kk < 2; ++kk) {
      const int ks = (lg * 16 + kk * 64) ^ (l7 << 4);
      bf16x8 af[2], bfr[6];
#pragma unroll
      for (int mi = 0; mi < 2; ++mi)
        af[mi] = *(const bf16x8*)(Ab + (wm0 + mi * 16 + l15) * 128 + ks);
#pragma unroll
      for (int nj = 0; nj < 6; ++nj)
        bfr[nj] = *(const bf16x8*)(Bb + (wn0 + nj * 16 + l15) * 128 + ks);
#pragma unroll
      for (int mi = 0; mi < 2; ++mi)
#pragma unroll
        for (int nj = 0; nj < 6; ++nj)
          acc[mi][nj] = __builtin_amdgcn_mfma_f32_16x16x32_bf16(
              af[mi], bfr[nj], acc[mi][nj], 0, 0, 0);
    }
    cur ^= 1;
  }

#pragma unroll
  for (int nj = 0; nj < 6; ++nj) {
    const int n = wn0 + nj * 16 + l15;
    const float bi = bias[n];
#pragma unroll
    for (int mi = 0; mi < 2; ++mi) {
      const int mb = bm0 + wm0 + mi * 16 + lg * 4;
#pragma unroll
      for (int r = 0; r < 4; ++r)
        C[(size_t)(mb + r) * 192 + n] = __float2bfloat16(acc[mi][nj][r] + bi);
    }
  }
}

// ------------- full-K GEMM (K=192, BM=64): 48KB LDS, 3 blocks/CU -----------
template <int MODE>
__global__ __launch_bounds__(256) void gemm_fullk_kernel(
    const __hip_bfloat16* __restrict__ A, const __hip_bfloat16* __restrict__ W,
    const float* __restrict__ bias, const __hip_bfloat16* __restrict__ res,
    const float* __restrict__ xin, void* __restrict__ Cout, int N) {
  __shared__ __hip_bfloat16 Asm[3 * 64 * 64];   // 24576 B
  __shared__ __hip_bfloat16 Bsm[3 * 64 * 64];   // 24576 B

  const int tid = threadIdx.x;
  const int lane = tid & 63;
  const int wave = tid >> 6;

  const int gx = gridDim.x;
  const int lid = blockIdx.y * gx + blockIdx.x;
  const int seq = lid >> 3;
  const int bm0 = (((lid & 7) << 7) + seq / gx) << 6;   // 1024 m-blocks, XCD-paneled
  const int bn0 = (seq % gx) * 64;

  const int wm0 = (wave >> 1) * 32;
  const int wn0 = (wave & 1) * 32;
  const int l15 = lane & 15;
  const int l7 = lane & 7;
  const int lg = lane >> 4;

  // stage A: 1536 granules (3 sections of [64][64], XOR-swizzled source)
#pragma unroll
  for (int it = 0; it < 6; ++it) {
    int ci = tid + it * 256;
    int sec = ci >> 9, ri = ci & 511;
    int r = ri >> 3, c = ri & 7;
    int sc = c ^ (r & 7);
    const __hip_bfloat16* src = A + (size_t)(bm0 + r) * 192 + sec * 64 + sc * 8;
    __builtin_amdgcn_global_load_lds((gv_t*)src, (lv_t*)&Asm[ci * 8], 16, 0, 0);
  }
  // stage B: 1536 granules
#pragma unroll
  for (int it = 0; it < 6; ++it) {
    int ci = tid + it * 256;
    int sec = ci >> 9, ri = ci & 511;
    int r = ri >> 3, c = ri & 7;
    int sc = c ^ (r & 7);
    const __hip_bfloat16* src = W + (size_t)(bn0 + r) * 192 + sec * 64 + sc * 8;
    __builtin_amdgcn_global_load_lds((gv_t*)src, (lv_t*)&Bsm[ci * 8], 16, 0, 0);
  }
  __syncthreads();

  f32x4 acc[2][2] = {};
  const char* Ab = (const char*)Asm;
  const char* Bb = (const char*)Bsm;
#pragma unroll
  for (int kk = 0; kk < 6; ++kk) {
    const int sec = kk >> 1, k2 = kk & 1;
    const int ks = (lg * 16 + k2 * 64) ^ (l7 << 4);
    bf16x8 af[2], bfr[2];
#pragma unroll
    for (int mi = 0; mi < 2; ++mi)
      af[mi] = *(const bf16x8*)(Ab + sec * 8192 + (wm0 + mi * 16 + l15) * 128 + ks);
#pragma unroll
    for (int nj = 0; nj < 2; ++nj)
      bfr[nj] = *(const bf16x8*)(Bb + sec * 8192 + (wn0 + nj * 16 + l15) * 128 + ks);
#pragma unroll
    for (int mi = 0; mi < 2; ++mi)
#pragma unroll
      for (int nj = 0; nj < 2; ++nj) {
        if constexpr (MODE == 2)
          acc[mi][nj] = __builtin_amdgcn_mfma_f32_16x16x32_bf16(
              bfr[nj], af[mi], acc[mi][nj], 0, 0, 0);   // D[row=n][col=m]
        else
          acc[mi][nj] = __builtin_amdgcn_mfma_f32_16x16x32_bf16(
              af[mi], bfr[nj], acc[mi][nj], 0, 0, 0);   // D[row=m][col=n]
      }
  }

  if constexpr (MODE == 2) {
    float* Cf = (float*)Cout;
#pragma unroll
    for (int nj = 0; nj < 2; ++nj) {
      const int n0 = bn0 + wn0 + nj * 16 + lg * 4;
      const f32x4 bi4 = *(const f32x4*)(bias + n0);
#pragma unroll
      for (int mi = 0; mi < 2; ++mi) {
        const int m = bm0 + wm0 + mi * 16 + l15;   // col = lane&15 -> m
        const int b = m >> 10;
        const int ll = m & 1023;
        const f32x4 xv = *(const f32x4*)(xin + (size_t)((ll << 6) | b) * 768 + n0);
        const size_t ob = (((size_t)(b >> 4) * 768 + n0) * 16 + (b & 15)) * 1024 + ll;
#pragma unroll
        for (int r = 0; r < 4; ++r)
          Cf[ob + (size_t)r * 16384] = acc[mi][nj][r] + bi4[r] + xv[r];
      }
    }
  } else {
    __hip_bfloat16* Cb = (__hip_bfloat16*)Cout;
#pragma unroll
    for (int nj = 0; nj < 2; ++nj) {
      const int n = bn0 + wn0 + nj * 16 + l15;
      const float bi = bias[n];
#pragma unroll
      for (int mi = 0; mi < 2; ++mi) {
        const int mb = bm0 + wm0 + mi * 16 + lg * 4;
        f32x4 v = acc[mi][nj];
#pragma unroll
        for (int r = 0; r < 4; ++r) {
          const int m = mb + r;
          float val = v[r] + bi;
          if constexpr (MODE == 1) val += __bfloat162float(res[(size_t)m * N + n]);
          Cb[(size_t)m * N + n] = __float2bfloat16(val);
        }
      }
    }
  }
}

// all six weights in one launch; i is a global float4 index
__global__ __launch_bounds__(256) void cvt_weights_kernel(
    const float* __restrict__ s0, const float* __restrict__ s1,
    const float* __restrict__ s2, const float* __restrict__ s3,
    const float* __restrict__ s4, const float* __restrict__ s5,
    __hip_bfloat16* __restrict__ d0, __hip_bfloat16* __restrict__ d1,
    __hip_bfloat16* __restrict__ d2, __hip_bfloat16* __restrict__ d3,
    __hip_bfloat16* __restrict__ d4, __hip_bfloat16* __restrict__ d5) {
  int i = blockIdx.x * 256 + threadIdx.x;   // 0..116735
  const float* src; __hip_bfloat16* dst; int off;
  if      (i < 36864)  { src = s0; dst = d0; off = i; }
  else if (i < 39936)  { src = s1; dst = d1; off = i - 36864; }
  else if (i < 43008)  { src = s2; dst = d2; off = i - 39936; }
  else if (i < 70656)  { src = s3; dst = d3; off = i - 43008; }
  else if (i < 79872)  { src = s4; dst = d4; off = i - 70656; }
  else                 { src = s5; dst = d5; off = i - 79872; }
  ((uint2*)dst)[off] = pack_bf16x4(((const float4*)src)[off]);
}

// ------- Fused bottleneck: convA -> convB -> +res -> GeLU -> LN ------------
__global__ __launch_bounds__(256, 2) void bottleneck_kernel(
    const __hip_bfloat16* __restrict__ xs0,
    const __hip_bfloat16* __restrict__ wA, const float* __restrict__ bA,
    const __hip_bfloat16* __restrict__ wB, const float* __restrict__ bB,
    const float* __restrict__ ln_g, const float* __restrict__ ln_b,
    __hip_bfloat16* __restrict__ xs_sp, __hip_bfloat16* __restrict__ ln_sp) {
  __shared__ __hip_bfloat16 xt[3 * 64 * 64];    // 24 KB
  __shared__ __hip_bfloat16 wAs[3 * 64 * 64];   // 24 KB
  __shared__ __hip_bfloat16 wBs[192 * 64];      // 24 KB
  __shared__ __hip_bfloat16 a2[64 * 64];        // 8 KB (stats overlaid later)

  const int tid = threadIdx.x;
  const int lane = tid & 63;
  const int wave = tid >> 6;
  const int bm0 = blockIdx.x * 64;
  const int l15 = lane & 15;
  const int lg = lane >> 4;
  const int wm0 = (wave >> 1) * 32;

#pragma unroll
  for (int it = 0; it < 6; ++it) {
    int ci = tid + it * 256;
    int sec = ci >> 9, ri = ci & 511;
    int r = ri >> 3, c = ri & 7;
    int sc = c ^ (r & 7);
    const __hip_bfloat16* src = xs0 + (size_t)(bm0 + r) * 192 + sec * 64 + sc * 8;
    __builtin_amdgcn_global_load_lds((gv_t*)src, (lv_t*)&xt[ci * 8], 16, 0, 0);
  }
#pragma unroll
  for (int it = 0; it < 6; ++it) {
    int ci = tid + it * 256;
    int sec = ci >> 9, ri = ci & 511;
    int r = ri >> 3, c = ri & 7;
    int sc = c ^ (r & 7);
    const __hip_bfloat16* src = wA + (size_t)r * 192 + sec * 64 + sc * 8;
    __builtin_amdgcn_global_load_lds((gv_t*)src, (lv_t*)&wAs[ci * 8], 16, 0, 0);
  }
#pragma unroll
  for (int it = 0; it < 6; ++it) {
    int ci = tid + it * 256;
    int r = ci >> 3, c = ci & 7;
    int sc = c ^ (r & 7);
    const __hip_bfloat16* src = wB + (size_t)r * 64 + sc * 8;
    __builtin_amdgcn_global_load_lds((gv_t*)src, (lv_t*)&wBs[ci * 8], 16, 0, 0);
  }
  __syncthreads();

  // ---- pass 1: a = xs0 @ wA^T + bA  (out 64x64, wave tile 32x32) ----
  {
    const int wn0 = (wave & 1) * 32;
    f32x4 acc1[2][2] = {};
    const char* Ab = (const char*)xt;
    const char* Bb = (const char*)wAs;
#pragma unroll
    for (int kk = 0; kk < 6; ++kk) {
      const int sec = kk >> 1, k2 = kk & 1;
      const int ks = (lg * 16 + k2 * 64) ^ ((l15 & 7) << 4);
      bf16x8 af[2], bfr[2];
#pragma unroll
      for (int mi = 0; mi < 2; ++mi)
        af[mi] = *(const bf16x8*)(Ab + sec * 8192 + (wm0 + mi * 16 + l15) * 128 + ks);
#pragma unroll
      for (int nj = 0; nj < 2; ++nj)
        bfr[nj] = *(const bf16x8*)(Bb + sec * 8192 + (wn0 + nj * 16 + l15) * 128 + ks);
#pragma unroll
      for (int mi = 0; mi < 2; ++mi)
#pragma unroll
        for (int nj = 0; nj < 2; ++nj)
          acc1[mi][nj] = __builtin_amdgcn_mfma_f32_16x16x32_bf16(
              af[mi], bfr[nj], acc1[mi][nj], 0, 0, 0);
    }
#pragma unroll
    for (int nj = 0; nj < 2; ++nj) {
      const int n = wn0 + nj * 16 + l15;
      const float bi = bA[n];
#pragma unroll
      for (int mi = 0; mi < 2; ++mi)
#pragma unroll
        for (int r = 0; r < 4; ++r) {
          const int row = wm0 + mi * 16 + lg * 4 + r;
          a2[row * 64 + (((n >> 3) ^ (row & 7)) << 3) + (n & 7)] =
              __float2bfloat16(acc1[mi][nj][r] + bi);
        }
    }
  }
  __syncthreads();

  // ---- pass 2: b = a @ wB^T (out 64x192, wave tile 32x96) ----
  const int wn0 = (wave & 1) * 96;
  f32x4 acc2[2][6] = {};
  {
    const char* Ab = (const char*)a2;
    const char* Bb = (const char*)wBs;
#pragma unroll
    for (int kk = 0; kk < 2; ++kk) {
      const int ks = (lg * 16 + kk * 64) ^ ((l15 & 7) << 4);
      bf16x8 af[2], bfr[6];
#pragma unroll
      for (int mi = 0; mi < 2; ++mi)
        af[mi] = *(const bf16x8*)(Ab + (wm0 + mi * 16 + l15) * 128 + ks);
#pragma unroll
      for (int nj = 0; nj < 6; ++nj)
        bfr[nj] = *(const bf16x8*)(Bb + (wn0 + nj * 16 + l15) * 128 + ks);
#pragma unroll
      for (int mi = 0; mi < 2; ++mi)
#pragma unroll
        for (int nj = 0; nj < 6; ++nj)
          acc2[mi][nj] = __builtin_amdgcn_mfma_f32_16x16x32_bf16(
              af[mi], bfr[nj], acc2[mi][nj], 0, 0, 0);
    }
  }
  __syncthreads();   // a2 dead; safe to overlay stats

  float* stats = (float*)a2;   // [row][half][2]

#pragma unroll
  for (int nj = 0; nj < 6; ++nj) {
    const int n = wn0 + nj * 16 + l15;
    const float bi = bB[n];
    const int sec = n >> 6, n6 = n & 63;
#pragma unroll
    for (int mi = 0; mi < 2; ++mi)
#pragma unroll
      for (int r = 0; r < 4; ++r) {
        const int row = wm0 + mi * 16 + lg * 4 + r;
        const int ei = sec * 4096 + row * 64 + (((n6 >> 3) ^ (row & 7)) << 3) + (n6 & 7);
        float v = acc2[mi][nj][r] + bi + __bfloat162float(xt[ei]);
        float ge = 0.5f * v * (1.0f + erff(v * 0.70710678118654752f));
        acc2[mi][nj][r] = ge;
        xt[ei] = __float2bfloat16(ge);
      }
  }
#pragma unroll
  for (int mi = 0; mi < 2; ++mi)
#pragma unroll
    for (int r = 0; r < 4; ++r) {
      float s1 = 0.0f, s2 = 0.0f;
#pragma unroll
      for (int nj = 0; nj < 6; ++nj) {
        float v = acc2[mi][nj][r];
        s1 += v;
        s2 += v * v;
      }
#pragma unroll
      for (int off = 1; off < 16; off <<= 1) {
        s1 += __shfl_xor(s1, off);
        s2 += __shfl_xor(s2, off);
      }
      if (l15 == 0) {
        const int row = wm0 + mi * 16 + lg * 4 + r;
        stats[row * 4 + (wave & 1) * 2 + 0] = s1;
        stats[row * 4 + (wave & 1) * 2 + 1] = s2;
      }
    }
  __syncthreads();

#pragma unroll
  for (int it = 0; it < 6; ++it) {
    int ci = tid + it * 256;
    int row = ci / 24, gr = ci % 24;
    int sec = gr >> 3, g8i = gr & 7;
    bf16x8 g8 = *(const bf16x8*)&xt[sec * 4096 + row * 64 + ((g8i ^ (row & 7)) << 3)];
    float s1 = stats[row * 4 + 0] + stats[row * 4 + 2];
    float s2 = stats[row * 4 + 1] + stats[row * 4 + 3];
    float mean = s1 * (1.0f / 192.0f);
    float var = s2 * (1.0f / 192.0f) - mean * mean;
    float rstd = rsqrtf(var + 1e-5f);
    const int m_l = bm0 + row;
    const size_t dst = ((size_t)(((m_l & 63) << 10) | (m_l >> 6))) * 192 + gr * 8;
    bf16x8 lnv;
#pragma unroll
    for (int u = 0; u < 8; ++u) {
      float g = (float)g8[u];
      lnv[u] = (__bf16)((g - mean) * rstd * ln_g[gr * 8 + u] + ln_b[gr * 8 + u]);
    }
    *(bf16x8*)(xs_sp + dst) = g8;
    *(bf16x8*)(ln_sp + dst) = lnv;
  }
}

// ---------------- Neighborhood attention: K/V-halo LDS only ----------------
// Block = one (16x16 pixel tile, head), 256 threads, 1 pixel/lane.
// LDS = 45KB K/V halo only -> 3 blocks/CU. Q read from global per-t (L2-hot).
__global__ __launch_bounds__(256, 3) void natten_kernel(
    const __hip_bfloat16* __restrict__ qkv, const float* __restrict__ rpb,
    __hip_bfloat16* __restrict__ o) {
  __shared__ __hip_bfloat16 kv_s[2816 * 8];   // 45056 B

  const int tid = threadIdx.x;
  const int bid = blockIdx.x;      // 1024 = 64 img * 2*2 tiles * 4 heads
  const int head = bid & 3;
  const int tj = (bid >> 2) & 1;
  const int ti = (bid >> 3) & 1;
  const int b = bid >> 4;

  const int hs = ti * 12;
  const int ws = tj * 12;
  const int i = ti * 16 + (tid >> 4);
  const int j = tj * 16 + (tid & 15);
  const int pix = (b << 10) + (i << 5) + j;
  const int ih0 = min(max(i - 2, 0), 27);
  const int iw0 = min(max(j - 2, 0), 27);
  const int oi = ih0 - hs;
  const int oj = iw0 - ws;
  const int dbh = ih0 - i + 4;
  const int dbw = iw0 - j + 4;
  const size_t kbase = (size_t)(b << 10) * 576 + 192 + head * 48;

  // stage K halo (2816 granules; pad slots read harmless in-bounds bytes)
#pragma unroll
  for (int it = 0; it < 11; ++it) {
    int ci = tid + it * 256;
    int r = ci / 7, c = ci % 7;
    int hr = r / 20, wr = r % 20;
    const __hip_bfloat16* src =
        qkv + kbase + (size_t)((hs + hr) * 32 + (ws + wr)) * 576 + c * 8;
    __builtin_amdgcn_global_load_lds((gv_t*)src, (lv_t*)&kv_s[ci * 8], 16, 0, 0);
  }

  float s[25];
#pragma unroll
  for (int x = 0; x < 5; ++x)
#pragma unroll
    for (int y = 0; y < 5; ++y)
      s[x * 5 + y] = rpb[head * 81 + (dbh + x) * 9 + (dbw + y)] * 6.9282032302755092f;

  __syncthreads();

  // QK t-outer; own-Q chunk loaded from global per t (16B, L2-resident)
  const bf16x8* qg = (const bf16x8*)(qkv + (size_t)pix * 576 + head * 48);
  const char* kvb = (const char*)kv_s + (oi * 20 + oj) * 112;
#pragma unroll
  for (int t = 0; t < 6; ++t) {
    const bf16x8 qv = qg[t];
#pragma unroll
    for (int x = 0; x < 5; ++x) {
#pragma unroll
      for (int y = 0; y < 5; ++y) {
        const bf16x8 kv = *(const bf16x8*)(kvb + (x * 20 + y) * 112 + t * 16);
        float a = 0.0f;
#pragma unroll
        for (int u = 0; u < 8; ++u) a += (float)qv[u] * (float)kv[u];
        s[x * 5 + y] += a;
      }
    }
  }
  __syncthreads();

  // stage V halo (same slots)
#pragma unroll
  for (int it = 0; it < 11; ++it) {
    int ci = tid + it * 256;
    int r = ci / 7, c = ci % 7;
    int hr = r / 20, wr = r % 20;
    const __hip_bfloat16* src =
        qkv + kbase + 192 + (size_t)((hs + hr) * 32 + (ws + wr)) * 576 + c * 8;
    __builtin_amdgcn_global_load_lds((gv_t*)src, (lv_t*)&kv_s[ci * 8], 16, 0, 0);
  }

  float mx = s[0];
#pragma unroll
  for (int n = 1; n < 25; ++n) mx = fmaxf(mx, s[n]);
  float sum = 0.0f;
#pragma unroll
  for (int n = 0; n < 25; ++n) {
    s[n] = __expf((s[n] - mx) * 0.14433756729740643f);
    sum += s[n];
  }
  const float inv = 1.0f / sum;

  __syncthreads();

  bf16x8* op = (bf16x8*)(o + (size_t)pix * 192 + head * 48);
#pragma unroll
  for (int t = 0; t < 6; ++t) {
    float pv[8] = {};
#pragma unroll
    for (int x = 0; x < 5; ++x) {
#pragma unroll
      for (int y = 0; y < 5; ++y) {
        const bf16x8 vv = *(const bf16x8*)(kvb + (x * 20 + y) * 112 + t * 16);
        const float w = s[x * 5 + y];
#pragma unroll
        for (int u = 0; u < 8; ++u) pv[u] += w * (float)vv[u];
      }
    }
    bf16x8 ov;
#pragma unroll
    for (int u = 0; u < 8; ++u) ov[u] = (__bf16)(pv[u] * inv);
    op[t] = ov;
  }
}

extern "C" void kernel_launch(void* const* d_in, const int* in_sizes, int n_in,
                              void* d_out, int out_size, void* d_ws, size_t ws_size,
                              hipStream_t stream) {
  const float* x       = (const float*)d_in[0];
  const float* fc1_w   = (const float*)d_in[1];
  const float* fc1_b   = (const float*)d_in[2];
  const float* convA_w = (const float*)d_in[3];
  const float* convA_b = (const float*)d_in[4];
  const float* convB_w = (const float*)d_in[5];
  const float* convB_b = (const float*)d_in[6];
  const float* ln_g    = (const float*)d_in[7];
  const float* ln_b    = (const float*)d_in[8];
  const float* qkv_w   = (const float*)d_in[9];
  const float* qkv_b   = (const float*)d_in[10];
  const float* rpb     = (const float*)d_in[11];
  const float* proj_w  = (const float*)d_in[12];
  const float* proj_b  = (const float*)d_in[13];
  const float* fc2_w   = (const float*)d_in[14];
  const float* fc2_b   = (const float*)d_in[15];
  float* out = (float*)d_out;

  char* W0 = (char*)d_ws;
  __hip_bfloat16* wfc1  = (__hip_bfloat16*)W0;
  __hip_bfloat16* wcvA  = wfc1 + 147456;
  __hip_bfloat16* wcvB  = wcvA + 12288;
  __hip_bfloat16* wqkv  = wcvB + 12288;
  __hip_bfloat16* wproj = wqkv + 110592;
  __hip_bfloat16* wfc2  = wproj + 36864;
  __hip_bfloat16* reg1  = wfc2 + 147456;                       // 37,748,736 elems
  __hip_bfloat16* xs0   = reg1;
  __hip_bfloat16* qkvb  = reg1;                                // alias after xs0 dead
  __hip_bfloat16* ybuf  = reg1;                                // alias after qkv dead
  __hip_bfloat16* xs_sp = reg1 + 37748736;                     // 12,582,912
  __hip_bfloat16* ln_sp = xs_sp + 12582912;                    // 12,582,912
  __hip_bfloat16* obuf  = ln_sp;                               // reuse after qkv GEMM

  // weights -> bf16 (one launch; 116736 float4s)
  cvt_weights_kernel<<<456, 256, 0, stream>>>(
      fc1_w, convA_w, convB_w, qkv_w, proj_w, fc2_w,
      wfc1, wcvA, wcvB, wqkv, wproj, wfc2);

  // 1. fc1 (fp32 A, in-register cvt)
  fc1_kernel<<<512, 512, 0, stream>>>(x, wfc1, fc1_b, xs0);
  // 2. fused bottleneck -> xs_sp, ln_sp
  bottleneck_kernel<<<1024, 256, 0, stream>>>(
      xs0, wcvA, convA_b, wcvB, convB_b, ln_g, ln_b, xs_sp, ln_sp);
  // 3. qkv (full-K BM=64)
  gemm_fullk_kernel<0><<<dim3(9, 1024), 256, 0, stream>>>(
      ln_sp, wqkv, qkv_b, nullptr, nullptr, qkvb, 576);
  // 4. natten
  natten_kernel<<<1024, 256, 0, stream>>>(qkvb, rpb, obuf);
  // 5. proj + residual(xs_sp) (full-K BM=64)
  gemm_fullk_kernel<1><<<dim3(3, 1024), 256, 0, stream>>>(
      obuf, wproj, proj_b, xs_sp, nullptr, ybuf, 192);
  // 6. fc2 + residual(x) + permuted scatter (full-K BM=64)
  gemm_fullk_kernel<2><<<dim3(12, 1024), 256, 0, stream>>>(
      ybuf, wfc2, fc2_b, nullptr, x, (void*)out, 768);
}

// Round 11
// 489.880 us; speedup vs baseline: 1.0561x; 1.0561x over previous
//
#include <hip/hip_runtime.h>
#include <hip/hip_bf16.h>
#include <math.h>

// L=1024, BT=64, D=768, HID=192, NH=4, hd=48, K=5, Hh=Ww=32, T=16, M=65536
//
//  cvt: weights -> bf16 (one launch). x stays fp32 (fc1 converts in-register).
//  1. xs0   = x @ fc1_w.T + b      (M x 192) bf16  [fc1: fp32-A reg-staged]
//  2. bottleneck fused: a=xs0@cvA.T; b=a@cvB.T; g=gelu(b+bB+xs0);
//     xs_sp[spatial]=g; ln_sp[spatial]=LN(g)
//  3. qkv   = ln_sp @ qkv_w.T + b  -> HEAD-MAJOR planes [(p*4+h)][m][48]
//  4. natten -> o (M x 192)        (K/V-halo LDS 45KB, Q in regs, 3 blk/CU)
//  5. y     = o @ proj_w.T + b + xs_sp             [full-K BM=128]
//  6. out   = scatter(y @ fc2_w.T + b + x) fp32 permuted, swapped-mfma

typedef __attribute__((ext_vector_type(4))) float f32x4;
typedef __attribute__((ext_vector_type(8))) __bf16 bf16x8;
typedef const __attribute__((address_space(1))) void gv_t;
typedef __attribute__((address_space(3))) void lv_t;

#define PLANE 3145728   // 65536*48 elements per (p,head) plane

__device__ __forceinline__ uint2 pack_bf16x4(float4 v) {
  union { unsigned short u[4]; uint2 d; } o;
  __hip_bfloat16 b0 = __float2bfloat16(v.x);
  __hip_bfloat16 b1 = __float2bfloat16(v.y);
  __hip_bfloat16 b2 = __float2bfloat16(v.z);
  __hip_bfloat16 b3 = __float2bfloat16(v.w);
  o.u[0] = *(unsigned short*)&b0; o.u[1] = *(unsigned short*)&b1;
  o.u[2] = *(unsigned short*)&b2; o.u[3] = *(unsigned short*)&b3;
  return o.d;
}

// ---------------- fc1: C(Mx192) = X(fp32, Mx768) @ W^T + bias, bf16 out ----
__global__ __launch_bounds__(512, 4) void fc1_kernel(
    const float* __restrict__ X, const __hip_bfloat16* __restrict__ W,
    const float* __restrict__ bias, __hip_bfloat16* __restrict__ C) {
  __shared__ __hip_bfloat16 Asm[2][128 * 64];   // 32 KB
  __shared__ __hip_bfloat16 Bsm[2][192 * 64];   // 48 KB

  const int tid = threadIdx.x;
  const int lane = tid & 63;
  const int wave = tid >> 6;
  const int lid = blockIdx.x;                   // 512 blocks
  const int bm0 = (((lid & 7) << 6) + (lid >> 3)) << 7;   // m-panel XCD swizzle
  const int wm0 = (wave >> 1) * 32;
  const int wn0 = (wave & 1) * 96;
  const int l15 = lane & 15;
  const int l7 = lane & 7;
  const int lg = lane >> 4;

  f32x4 acc[2][6] = {};
  float4 ar[4];

  auto stageB = [&](int buf, int k0) {
#pragma unroll
    for (int it = 0; it < 3; ++it) {
      int ci = tid + it * 512;                  // 0..1535
      int r = ci >> 3, c = ci & 7;
      int sc = c ^ (r & 7);
      const __hip_bfloat16* src = W + (size_t)r * 768 + k0 + sc * 8;
      __builtin_amdgcn_global_load_lds((gv_t*)src, (lv_t*)&Bsm[buf][ci * 8], 16, 0, 0);
    }
  };
  auto loadA = [&](int k0) {
#pragma unroll
    for (int q = 0; q < 2; ++q) {
      int ci = tid + q * 512;                   // 0..1023
      int r = ci >> 3, c = ci & 7;
      int sc = c ^ (r & 7);
      const float* src = X + (size_t)(bm0 + r) * 768 + k0 + sc * 8;
      ar[2 * q] = *(const float4*)src;
      ar[2 * q + 1] = *(const float4*)(src + 4);
    }
  };
  auto writeA = [&](int buf) {
#pragma unroll
    for (int q = 0; q < 2; ++q) {
      int ci = tid + q * 512;
      uint2 a = pack_bf16x4(ar[2 * q]);
      uint2 b = pack_bf16x4(ar[2 * q + 1]);
      uint4 w; w.x = a.x; w.y = a.y; w.z = b.x; w.w = b.y;
      *(uint4*)&Asm[buf][ci * 8] = w;
    }
  };

  stageB(0, 0);
  loadA(0);
  int cur = 0;
  for (int kt = 0; kt < 12; ++kt) {
    writeA(cur);
    __syncthreads();
    if (kt < 11) { stageB(cur ^ 1, (kt + 1) * 64); loadA((kt + 1) * 64); }
    const char* Ab = (const char*)&Asm[cur][0];
    const char* Bb = (const char*)&Bsm[cur][0];
#pragma unroll
    for (int kk = 0; kk < 2; ++kk) {
      const int ks = (lg * 16 + kk * 64) ^ (l7 << 4);
      bf16x8 af[2], bfr[6];
#pragma unroll
      for (int mi = 0; mi < 2; ++mi)
        af[mi] = *(const bf16x8*)(Ab + (wm0 + mi * 16 + l15) * 128 + ks);
#pragma unroll
      for (int nj = 0; nj < 6; ++nj)
        bfr[nj] = *(const bf16x8*)(Bb + (wn0 + nj * 16 + l15) * 128 + ks);
#pragma unroll
      for (int mi = 0; mi < 2; ++mi)
#pragma unroll
        for (int nj = 0; nj < 6; ++nj)
          acc[mi][nj] = __builtin_amdgcn_mfma_f32_16x16x32_bf16(
              af[mi], bfr[nj], acc[mi][nj], 0, 0, 0);
    }
    cur ^= 1;
  }

#pragma unroll
  for (int nj = 0; nj < 6; ++nj) {
    const int n = wn0 + nj * 16 + l15;
    const float bi = bias[n];
#pragma unroll
    for (int mi = 0; mi < 2; ++mi) {
      const int mb = bm0 + wm0 + mi * 16 + lg * 4;
#pragma unroll
      for (int r = 0; r < 4; ++r)
        C[(size_t)(mb + r) * 192 + n] = __float2bfloat16(acc[mi][nj][r] + bi);
    }
  }
}

// ------------- full-K GEMM (K=192, BM=128): single-stage, 73.7KB LDS -------
// MODE 0: bf16 -> head-major qkv planes [(p*4+h)][m][48].
// MODE 1: + res, bf16 [m][N]. MODE 2: swapped mfma, fp32 permuted scatter + x.
template <int MODE>
__global__ __launch_bounds__(256) void gemm_fullk_kernel(
    const __hip_bfloat16* __restrict__ A, const __hip_bfloat16* __restrict__ W,
    const float* __restrict__ bias, const __hip_bfloat16* __restrict__ res,
    const float* __restrict__ xin, void* __restrict__ Cout, int N) {
  __shared__ __hip_bfloat16 Asm[3 * 128 * 64];  // 49152 B
  __shared__ __hip_bfloat16 Bsm[3 * 64 * 64];   // 24576 B

  const int tid = threadIdx.x;
  const int lane = tid & 63;
  const int wave = tid >> 6;

  const int gx = gridDim.x;
  const int lid = blockIdx.y * gx + blockIdx.x;
  const int seq = lid >> 3;
  const int bm0 = (((lid & 7) << 6) + seq / gx) << 7;     // m-panel XCD swizzle
  const int bn0 = (seq % gx) * 64;

  const int wm0 = (wave >> 1) * 64;
  const int wn0 = (wave & 1) * 32;
  const int l15 = lane & 15;
  const int l7 = lane & 7;
  const int lg = lane >> 4;

#pragma unroll
  for (int it = 0; it < 12; ++it) {
    int ci = tid + it * 256;
    int sec = ci >> 10, ri = ci & 1023;
    int r = ri >> 3, c = ri & 7;
    int sc = c ^ (r & 7);
    const __hip_bfloat16* src = A + (size_t)(bm0 + r) * 192 + sec * 64 + sc * 8;
    __builtin_amdgcn_global_load_lds((gv_t*)src, (lv_t*)&Asm[ci * 8], 16, 0, 0);
  }
#pragma unroll
  for (int it = 0; it < 6; ++it) {
    int ci = tid + it * 256;
    int sec = ci >> 9, ri = ci & 511;
    int r = ri >> 3, c = ri & 7;
    int sc = c ^ (r & 7);
    const __hip_bfloat16* src = W + (size_t)(bn0 + r) * 192 + sec * 64 + sc * 8;
    __builtin_amdgcn_global_load_lds((gv_t*)src, (lv_t*)&Bsm[ci * 8], 16, 0, 0);
  }
  __syncthreads();

  f32x4 acc[4][2] = {};
  const char* Ab = (const char*)Asm;
  const char* Bb = (const char*)Bsm;
#pragma unroll
  for (int kk = 0; kk < 6; ++kk) {
    const int sec = kk >> 1, k2 = kk & 1;
    const int ks = (lg * 16 + k2 * 64) ^ (l7 << 4);
    bf16x8 af[4], bfr[2];
#pragma unroll
    for (int mi = 0; mi < 4; ++mi)
      af[mi] = *(const bf16x8*)(Ab + sec * 16384 + (wm0 + mi * 16 + l15) * 128 + ks);
#pragma unroll
    for (int nj = 0; nj < 2; ++nj)
      bfr[nj] = *(const bf16x8*)(Bb + sec * 8192 + (wn0 + nj * 16 + l15) * 128 + ks);
#pragma unroll
    for (int mi = 0; mi < 4; ++mi)
#pragma unroll
      for (int nj = 0; nj < 2; ++nj) {
        if constexpr (MODE == 2)
          acc[mi][nj] = __builtin_amdgcn_mfma_f32_16x16x32_bf16(
              bfr[nj], af[mi], acc[mi][nj], 0, 0, 0);   // D[row=n][col=m]
        else
          acc[mi][nj] = __builtin_amdgcn_mfma_f32_16x16x32_bf16(
              af[mi], bfr[nj], acc[mi][nj], 0, 0, 0);   // D[row=m][col=n]
      }
  }

  if constexpr (MODE == 2) {
    float* Cf = (float*)Cout;
#pragma unroll
    for (int nj = 0; nj < 2; ++nj) {
      const int n0 = bn0 + wn0 + nj * 16 + lg * 4;
      const f32x4 bi4 = *(const f32x4*)(bias + n0);
#pragma unroll
      for (int mi = 0; mi < 4; ++mi) {
        const int m = bm0 + wm0 + mi * 16 + l15;   // col = lane&15 -> m
        const int b = m >> 10;
        const int ll = m & 1023;
        const f32x4 xv = *(const f32x4*)(xin + (size_t)((ll << 6) | b) * 768 + n0);
        const size_t ob = (((size_t)(b >> 4) * 768 + n0) * 16 + (b & 15)) * 1024 + ll;
#pragma unroll
        for (int r = 0; r < 4; ++r)
          Cf[ob + (size_t)r * 16384] = acc[mi][nj][r] + bi4[r] + xv[r];
      }
    }
  } else if constexpr (MODE == 0) {
    // head-major qkv planes: n -> (p = n/192, h = (n%192)/48, d = n%48)
    __hip_bfloat16* Cb = (__hip_bfloat16*)Cout;
#pragma unroll
    for (int nj = 0; nj < 2; ++nj) {
      const int n = bn0 + wn0 + nj * 16 + l15;
      const int p = n / 192;
      const int rem = n - p * 192;
      const int h = rem / 48;
      const int d = rem - h * 48;
      const size_t plane = (size_t)(p * 4 + h) * PLANE;
      const float bi = bias[n];
#pragma unroll
      for (int mi = 0; mi < 4; ++mi) {
        const int mb = bm0 + wm0 + mi * 16 + lg * 4;
#pragma unroll
        for (int r = 0; r < 4; ++r)
          Cb[plane + (size_t)(mb + r) * 48 + d] =
              __float2bfloat16(acc[mi][nj][r] + bi);
      }
    }
  } else {
    __hip_bfloat16* Cb = (__hip_bfloat16*)Cout;
#pragma unroll
    for (int nj = 0; nj < 2; ++nj) {
      const int n = bn0 + wn0 + nj * 16 + l15;
      const float bi = bias[n];
#pragma unroll
      for (int mi = 0; mi < 4; ++mi) {
        const int mb = bm0 + wm0 + mi * 16 + lg * 4;
        f32x4 v = acc[mi][nj];
#pragma unroll
        for (int r = 0; r < 4; ++r) {
          const int m = mb + r;
          float val = v[r] + bi + __bfloat162float(res[(size_t)m * N + n]);
          Cb[(size_t)m * N + n] = __float2bfloat16(val);
        }
      }
    }
  }
}

// all six weights in one launch; i is a global float4 index
__global__ __launch_bounds__(256) void cvt_weights_kernel(
    const float* __restrict__ s0, const float* __restrict__ s1,
    const float* __restrict__ s2, const float* __restrict__ s3,
    const float* __restrict__ s4, const float* __restrict__ s5,
    __hip_bfloat16* __restrict__ d0, __hip_bfloat16* __restrict__ d1,
    __hip_bfloat16* __restrict__ d2, __hip_bfloat16* __restrict__ d3,
    __hip_bfloat16* __restrict__ d4, __hip_bfloat16* __restrict__ d5) {
  int i = blockIdx.x * 256 + threadIdx.x;   // 0..116735
  const float* src; __hip_bfloat16* dst; int off;
  if      (i < 36864)  { src = s0; dst = d0; off = i; }
  else if (i < 39936)  { src = s1; dst = d1; off = i - 36864; }
  else if (i < 43008)  { src = s2; dst = d2; off = i - 39936; }
  else if (i < 70656)  { src = s3; dst = d3; off = i - 43008; }
  else if (i < 79872)  { src = s4; dst = d4; off = i - 70656; }
  else                 { src = s5; dst = d5; off = i - 79872; }
  ((uint2*)dst)[off] = pack_bf16x4(((const float4*)src)[off]);
}

// ------- Fused bottleneck: convA -> convB -> +res -> GeLU -> LN ------------
__global__ __launch_bounds__(256, 2) void bottleneck_kernel(
    const __hip_bfloat16* __restrict__ xs0,
    const __hip_bfloat16* __restrict__ wA, const float* __restrict__ bA,
    const __hip_bfloat16* __restrict__ wB, const float* __restrict__ bB,
    const float* __restrict__ ln_g, const float* __restrict__ ln_b,
    __hip_bfloat16* __restrict__ xs_sp, __hip_bfloat16* __restrict__ ln_sp) {
  __shared__ __hip_bfloat16 xt[3 * 64 * 64];    // 24 KB
  __shared__ __hip_bfloat16 wAs[3 * 64 * 64];   // 24 KB
  __shared__ __hip_bfloat16 wBs[192 * 64];      // 24 KB
  __shared__ __hip_bfloat16 a2[64 * 64];        // 8 KB (stats overlaid later)

  const int tid = threadIdx.x;
  const int lane = tid & 63;
  const int wave = tid >> 6;
  const int bm0 = blockIdx.x * 64;
  const int l15 = lane & 15;
  const int lg = lane >> 4;
  const int wm0 = (wave >> 1) * 32;

#pragma unroll
  for (int it = 0; it < 6; ++it) {
    int ci = tid + it * 256;
    int sec = ci >> 9, ri = ci & 511;
    int r = ri >> 3, c = ri & 7;
    int sc = c ^ (r & 7);
    const __hip_bfloat16* src = xs0 + (size_t)(bm0 + r) * 192 + sec * 64 + sc * 8;
    __builtin_amdgcn_global_load_lds((gv_t*)src, (lv_t*)&xt[ci * 8], 16, 0, 0);
  }
#pragma unroll
  for (int it = 0; it < 6; ++it) {
    int ci = tid + it * 256;
    int sec = ci >> 9, ri = ci & 511;
    int r = ri >> 3, c = ri & 7;
    int sc = c ^ (r & 7);
    const __hip_bfloat16* src = wA + (size_t)r * 192 + sec * 64 + sc * 8;
    __builtin_amdgcn_global_load_lds((gv_t*)src, (lv_t*)&wAs[ci * 8], 16, 0, 0);
  }
#pragma unroll
  for (int it = 0; it < 6; ++it) {
    int ci = tid + it * 256;
    int r = ci >> 3, c = ci & 7;
    int sc = c ^ (r & 7);
    const __hip_bfloat16* src = wB + (size_t)r * 64 + sc * 8;
    __builtin_amdgcn_global_load_lds((gv_t*)src, (lv_t*)&wBs[ci * 8], 16, 0, 0);
  }
  __syncthreads();

  // ---- pass 1: a = xs0 @ wA^T + bA ----
  {
    const int wn0 = (wave & 1) * 32;
    f32x4 acc1[2][2] = {};
    const char* Ab = (const char*)xt;
    const char* Bb = (const char*)wAs;
#pragma unroll
    for (int kk = 0; kk < 6; ++kk) {
      const int sec = kk >> 1, k2 = kk & 1;
      const int ks = (lg * 16 + k2 * 64) ^ ((l15 & 7) << 4);
      bf16x8 af[2], bfr[2];
#pragma unroll
      for (int mi = 0; mi < 2; ++mi)
        af[mi] = *(const bf16x8*)(Ab + sec * 8192 + (wm0 + mi * 16 + l15) * 128 + ks);
#pragma unroll
      for (int nj = 0; nj < 2; ++nj)
        bfr[nj] = *(const bf16x8*)(Bb + sec * 8192 + (wn0 + nj * 16 + l15) * 128 + ks);
#pragma unroll
      for (int mi = 0; mi < 2; ++mi)
#pragma unroll
        for (int nj = 0; nj < 2; ++nj)
          acc1[mi][nj] = __builtin_amdgcn_mfma_f32_16x16x32_bf16(
              af[mi], bfr[nj], acc1[mi][nj], 0, 0, 0);
    }
#pragma unroll
    for (int nj = 0; nj < 2; ++nj) {
      const int n = wn0 + nj * 16 + l15;
      const float bi = bA[n];
#pragma unroll
      for (int mi = 0; mi < 2; ++mi)
#pragma unroll
        for (int r = 0; r < 4; ++r) {
          const int row = wm0 + mi * 16 + lg * 4 + r;
          a2[row * 64 + (((n >> 3) ^ (row & 7)) << 3) + (n & 7)] =
              __float2bfloat16(acc1[mi][nj][r] + bi);
        }
    }
  }
  __syncthreads();

  // ---- pass 2: b = a @ wB^T ----
  const int wn0 = (wave & 1) * 96;
  f32x4 acc2[2][6] = {};
  {
    const char* Ab = (const char*)a2;
    const char* Bb = (const char*)wBs;
#pragma unroll
    for (int kk = 0; kk < 2; ++kk) {
      const int ks = (lg * 16 + kk * 64) ^ ((l15 & 7) << 4);
      bf16x8 af[2], bfr[6];
#pragma unroll
      for (int mi = 0; mi < 2; ++mi)
        af[mi] = *(const bf16x8*)(Ab + (wm0 + mi * 16 + l15) * 128 + ks);
#pragma unroll
      for (int nj = 0; nj < 6; ++nj)
        bfr[nj] = *(const bf16x8*)(Bb + (wn0 + nj * 16 + l15) * 128 + ks);
#pragma unroll
      for (int mi = 0; mi < 2; ++mi)
#pragma unroll
        for (int nj = 0; nj < 6; ++nj)
          acc2[mi][nj] = __builtin_amdgcn_mfma_f32_16x16x32_bf16(
              af[mi], bfr[nj], acc2[mi][nj], 0, 0, 0);
    }
  }
  __syncthreads();   // a2 dead; safe to overlay stats

  float* stats = (float*)a2;

#pragma unroll
  for (int nj = 0; nj < 6; ++nj) {
    const int n = wn0 + nj * 16 + l15;
    const float bi = bB[n];
    const int sec = n >> 6, n6 = n & 63;
#pragma unroll
    for (int mi = 0; mi < 2; ++mi)
#pragma unroll
      for (int r = 0; r < 4; ++r) {
        const int row = wm0 + mi * 16 + lg * 4 + r;
        const int ei = sec * 4096 + row * 64 + (((n6 >> 3) ^ (row & 7)) << 3) + (n6 & 7);
        float v = acc2[mi][nj][r] + bi + __bfloat162float(xt[ei]);
        float ge = 0.5f * v * (1.0f + erff(v * 0.70710678118654752f));
        acc2[mi][nj][r] = ge;
        xt[ei] = __float2bfloat16(ge);
      }
  }
#pragma unroll
  for (int mi = 0; mi < 2; ++mi)
#pragma unroll
    for (int r = 0; r < 4; ++r) {
      float s1 = 0.0f, s2 = 0.0f;
#pragma unroll
      for (int nj = 0; nj < 6; ++nj) {
        float v = acc2[mi][nj][r];
        s1 += v;
        s2 += v * v;
      }
#pragma unroll
      for (int off = 1; off < 16; off <<= 1) {
        s1 += __shfl_xor(s1, off);
        s2 += __shfl_xor(s2, off);
      }
      if (l15 == 0) {
        const int row = wm0 + mi * 16 + lg * 4 + r;
        stats[row * 4 + (wave & 1) * 2 + 0] = s1;
        stats[row * 4 + (wave & 1) * 2 + 1] = s2;
      }
    }
  __syncthreads();

#pragma unroll
  for (int it = 0; it < 6; ++it) {
    int ci = tid + it * 256;
    int row = ci / 24, gr = ci % 24;
    int sec = gr >> 3, g8i = gr & 7;
    bf16x8 g8 = *(const bf16x8*)&xt[sec * 4096 + row * 64 + ((g8i ^ (row & 7)) << 3)];
    float s1 = stats[row * 4 + 0] + stats[row * 4 + 2];
    float s2 = stats[row * 4 + 1] + stats[row * 4 + 3];
    float mean = s1 * (1.0f / 192.0f);
    float var = s2 * (1.0f / 192.0f) - mean * mean;
    float rstd = rsqrtf(var + 1e-5f);
    const int m_l = bm0 + row;
    const size_t dst = ((size_t)(((m_l & 63) << 10) | (m_l >> 6))) * 192 + gr * 8;
    bf16x8 lnv;
#pragma unroll
    for (int u = 0; u < 8; ++u) {
      float g = (float)g8[u];
      lnv[u] = (__bf16)((g - mean) * rstd * ln_g[gr * 8 + u] + ln_b[gr * 8 + u]);
    }
    *(bf16x8*)(xs_sp + dst) = g8;
    *(bf16x8*)(ln_sp + dst) = lnv;
  }
}

// ---------------- Neighborhood attention: head-major planes ----------------
// qkv layout [(p*4+h)][m][48]. Block = (16x16 tile, head), 1 px/lane.
// Q: 96B/lane coalesced once into 24 VGPR. K/V halo: contiguous 96B/px runs
// staged to 45KB LDS (7-granule pad rows -> conflict-free reads). 3 blk/CU.
__global__ __launch_bounds__(256, 3) void natten_kernel(
    const __hip_bfloat16* __restrict__ qkv, const float* __restrict__ rpb,
    __hip_bfloat16* __restrict__ o) {
  __shared__ __hip_bfloat16 kv_s[2816 * 8];   // 45056 B

  const int tid = threadIdx.x;
  const int bid = blockIdx.x;      // 1024 = 64 img * 2*2 tiles * 4 heads
  const int head = bid & 3;
  const int tj = (bid >> 2) & 1;
  const int ti = (bid >> 3) & 1;
  const int b = bid >> 4;

  const int hs = ti * 12;
  const int ws = tj * 12;
  const int i = ti * 16 + (tid >> 4);
  const int j = tj * 16 + (tid & 15);
  const int pix = (b << 10) + (i << 5) + j;
  const int ih0 = min(max(i - 2, 0), 27);
  const int iw0 = min(max(j - 2, 0), 27);
  const int oi = ih0 - hs;
  const int oj = iw0 - ws;
  const int dbh = ih0 - i + 4;
  const int dbw = iw0 - j + 4;

  const __hip_bfloat16* Kp = qkv + (size_t)(4 + head) * PLANE;
  const __hip_bfloat16* Vp = qkv + (size_t)(8 + head) * PLANE;

  // stage K halo: per halo pixel 96B contiguous (6 granules) + 1 pad granule
#pragma unroll
  for (int it = 0; it < 11; ++it) {
    int ci = tid + it * 256;
    int r = ci / 7, c = ci % 7;   // pad c==6 reads next pixel's bytes: in-bounds
    int hr = r / 20, wr = r % 20;
    const __hip_bfloat16* src =
        Kp + (size_t)((b << 10) + (hs + hr) * 32 + (ws + wr)) * 48 + c * 8;
    __builtin_amdgcn_global_load_lds((gv_t*)src, (lv_t*)&kv_s[ci * 8], 16, 0, 0);
  }

  // Q: own pixel's 96B, coalesced across lanes (plane is [m][48])
  bf16x8 qv[6];
  {
    const bf16x8* qg = (const bf16x8*)(qkv + (size_t)head * PLANE + (size_t)pix * 48);
#pragma unroll
    for (int t = 0; t < 6; ++t) qv[t] = qg[t];
  }

  float s[25];
#pragma unroll
  for (int x = 0; x < 5; ++x)
#pragma unroll
    for (int y = 0; y < 5; ++y)
      s[x * 5 + y] = rpb[head * 81 + (dbh + x) * 9 + (dbw + y)] * 6.9282032302755092f;

  __syncthreads();

  const char* kvb = (const char*)kv_s + (oi * 20 + oj) * 112;
#pragma unroll
  for (int t = 0; t < 6; ++t) {
    const bf16x8 q8 = qv[t];
#pragma unroll
    for (int x = 0; x < 5; ++x) {
#pragma unroll
      for (int y = 0; y < 5; ++y) {
        const bf16x8 kv = *(const bf16x8*)(kvb + (x * 20 + y) * 112 + t * 16);
        float a = 0.0f;
#pragma unroll
        for (int u = 0; u < 8; ++u) a += (float)q8[u] * (float)kv[u];
        s[x * 5 + y] += a;
      }
    }
  }
  __syncthreads();

  // stage V halo (same slots)
#pragma unroll
  for (int it = 0; it < 11; ++it) {
    int ci = tid + it * 256;
    int r = ci / 7, c = ci % 7;
    int hr = r / 20, wr = r % 20;
    const __hip_bfloat16* src =
        Vp + (size_t)((b << 10) + (hs + hr) * 32 + (ws + wr)) * 48 + c * 8;
    __builtin_amdgcn_global_load_lds((gv_t*)src, (lv_t*)&kv_s[ci * 8], 16, 0, 0);
  }

  float mx = s[0];
#pragma unroll
  for (int n = 1; n < 25; ++n) mx = fmaxf(mx, s[n]);
  float sum = 0.0f;
#pragma unroll
  for (int n = 0; n < 25; ++n) {
    s[n] = __expf((s[n] - mx) * 0.14433756729740643f);
    sum += s[n];
  }
  const float inv = 1.0f / sum;

  __syncthreads();

  bf16x8* op = (bf16x8*)(o + (size_t)pix * 192 + head * 48);
#pragma unroll
  for (int t = 0; t < 6; ++t) {
    float pv[8] = {};
#pragma unroll
    for (int x = 0; x < 5; ++x) {
#pragma unroll
      for (int y = 0; y < 5; ++y) {
        const bf16x8 vv = *(const bf16x8*)(kvb + (x * 20 + y) * 112 + t * 16);
        const float w = s[x * 5 + y];
#pragma unroll
        for (int u = 0; u < 8; ++u) pv[u] += w * (float)vv[u];
      }
    }
    bf16x8 ov;
#pragma unroll
    for (int u = 0; u < 8; ++u) ov[u] = (__bf16)(pv[u] * inv);
    op[t] = ov;
  }
}

extern "C" void kernel_launch(void* const* d_in, const int* in_sizes, int n_in,
                              void* d_out, int out_size, void* d_ws, size_t ws_size,
                              hipStream_t stream) {
  const float* x       = (const float*)d_in[0];
  const float* fc1_w   = (const float*)d_in[1];
  const float* fc1_b   = (const float*)d_in[2];
  const float* convA_w = (const float*)d_in[3];
  const float* convA_b = (const float*)d_in[4];
  const float* convB_w = (const float*)d_in[5];
  const float* convB_b = (const float*)d_in[6];
  const float* ln_g    = (const float*)d_in[7];
  const float* ln_b    = (const float*)d_in[8];
  const float* qkv_w   = (const float*)d_in[9];
  const float* qkv_b   = (const float*)d_in[10];
  const float* rpb     = (const float*)d_in[11];
  const float* proj_w  = (const float*)d_in[12];
  const float* proj_b  = (const float*)d_in[13];
  const float* fc2_w   = (const float*)d_in[14];
  const float* fc2_b   = (const float*)d_in[15];
  float* out = (float*)d_out;

  char* W0 = (char*)d_ws;
  __hip_bfloat16* wfc1  = (__hip_bfloat16*)W0;
  __hip_bfloat16* wcvA  = wfc1 + 147456;
  __hip_bfloat16* wcvB  = wcvA + 12288;
  __hip_bfloat16* wqkv  = wcvB + 12288;
  __hip_bfloat16* wproj = wqkv + 110592;
  __hip_bfloat16* wfc2  = wproj + 36864;
  __hip_bfloat16* reg1  = wfc2 + 147456;                       // 37,748,736 elems
  __hip_bfloat16* xs0   = reg1;
  __hip_bfloat16* qkvb  = reg1;                                // alias after xs0 dead
  __hip_bfloat16* ybuf  = reg1;                                // alias after qkv dead
  __hip_bfloat16* xs_sp = reg1 + 37748736;                     // 12,582,912
  __hip_bfloat16* ln_sp = xs_sp + 12582912;                    // 12,582,912
  __hip_bfloat16* obuf  = ln_sp;                               // reuse after qkv GEMM

  // weights -> bf16 (one launch; 116736 float4s)
  cvt_weights_kernel<<<456, 256, 0, stream>>>(
      fc1_w, convA_w, convB_w, qkv_w, proj_w, fc2_w,
      wfc1, wcvA, wcvB, wqkv, wproj, wfc2);

  // 1. fc1 (fp32 A, in-register cvt)
  fc1_kernel<<<512, 512, 0, stream>>>(x, wfc1, fc1_b, xs0);
  // 2. fused bottleneck -> xs_sp, ln_sp
  bottleneck_kernel<<<1024, 256, 0, stream>>>(
      xs0, wcvA, convA_b, wcvB, convB_b, ln_g, ln_b, xs_sp, ln_sp);
  // 3. qkv -> head-major planes
  gemm_fullk_kernel<0><<<dim3(9, 512), 256, 0, stream>>>(
      ln_sp, wqkv, qkv_b, nullptr, nullptr, qkvb, 576);
  // 4. natten (head-major planes)
  natten_kernel<<<1024, 256, 0, stream>>>(qkvb, rpb, obuf);
  // 5. proj + residual(xs_sp)
  gemm_fullk_kernel<1><<<dim3(3, 512), 256, 0, stream>>>(
      obuf, wproj, proj_b, xs_sp, nullptr, ybuf, 192);
  // 6. fc2 + residual(x) + permuted scatter
  gemm_fullk_kernel<2><<<dim3(12, 512), 256, 0, stream>>>(
      ybuf, wfc2, fc2_b, nullptr, x, (void*)out, 768);
}

// Round 12
// 298.501 us; speedup vs baseline: 1.7333x; 1.6411x over previous
//
#include <hip/hip_runtime.h>
#include <hip/hip_bf16.h>
#include <math.h>

// L=1024, BT=64, D=768, HID=192, NH=4, hd=48, K=5, Hh=Ww=32, T=16, M=65536
//
//  cvt: weights -> bf16 (one launch). x stays fp32 (fc1 converts in-register).
//  1. xs0   = x @ fc1_w.T + b      (M x 192) bf16  [fc1: fp32-A reg-staged]
//  2. bottleneck fused: a=xs0@cvA.T; b=a@cvB.T; g=gelu(b+bB+xs0);
//     xs_sp[spatial]=g; ln_sp[spatial]=LN(g)
//  3. qkv   = ln_sp @ qkv_w.T + b  -> HEAD-MAJOR planes [(p*4+h)][m][48]
//  4. natten -> o (M x 192)        all-LDS (q_s 24.6KB + kv_s 45KB) from planes
//  5. y     = o @ proj_w.T + b + xs_sp             [full-K BM=128]
//  6. out   = scatter(y @ fc2_w.T + b + x) fp32 permuted, swapped-mfma

typedef __attribute__((ext_vector_type(4))) float f32x4;
typedef __attribute__((ext_vector_type(8))) __bf16 bf16x8;
typedef const __attribute__((address_space(1))) void gv_t;
typedef __attribute__((address_space(3))) void lv_t;

#define PLANE 3145728   // 65536*48 elements per (p,head) plane

__device__ __forceinline__ uint2 pack_bf16x4(float4 v) {
  union { unsigned short u[4]; uint2 d; } o;
  __hip_bfloat16 b0 = __float2bfloat16(v.x);
  __hip_bfloat16 b1 = __float2bfloat16(v.y);
  __hip_bfloat16 b2 = __float2bfloat16(v.z);
  __hip_bfloat16 b3 = __float2bfloat16(v.w);
  o.u[0] = *(unsigned short*)&b0; o.u[1] = *(unsigned short*)&b1;
  o.u[2] = *(unsigned short*)&b2; o.u[3] = *(unsigned short*)&b3;
  return o.d;
}

// ---------------- fc1: C(Mx192) = X(fp32, Mx768) @ W^T + bias, bf16 out ----
__global__ __launch_bounds__(512, 4) void fc1_kernel(
    const float* __restrict__ X, const __hip_bfloat16* __restrict__ W,
    const float* __restrict__ bias, __hip_bfloat16* __restrict__ C) {
  __shared__ __hip_bfloat16 Asm[2][128 * 64];   // 32 KB
  __shared__ __hip_bfloat16 Bsm[2][192 * 64];   // 48 KB

  const int tid = threadIdx.x;
  const int lane = tid & 63;
  const int wave = tid >> 6;
  const int lid = blockIdx.x;                   // 512 blocks
  const int bm0 = (((lid & 7) << 6) + (lid >> 3)) << 7;   // m-panel XCD swizzle
  const int wm0 = (wave >> 1) * 32;
  const int wn0 = (wave & 1) * 96;
  const int l15 = lane & 15;
  const int l7 = lane & 7;
  const int lg = lane >> 4;

  f32x4 acc[2][6] = {};
  float4 ar[4];

  auto stageB = [&](int buf, int k0) {
#pragma unroll
    for (int it = 0; it < 3; ++it) {
      int ci = tid + it * 512;                  // 0..1535
      int r = ci >> 3, c = ci & 7;
      int sc = c ^ (r & 7);
      const __hip_bfloat16* src = W + (size_t)r * 768 + k0 + sc * 8;
      __builtin_amdgcn_global_load_lds((gv_t*)src, (lv_t*)&Bsm[buf][ci * 8], 16, 0, 0);
    }
  };
  auto loadA = [&](int k0) {
#pragma unroll
    for (int q = 0; q < 2; ++q) {
      int ci = tid + q * 512;                   // 0..1023
      int r = ci >> 3, c = ci & 7;
      int sc = c ^ (r & 7);
      const float* src = X + (size_t)(bm0 + r) * 768 + k0 + sc * 8;
      ar[2 * q] = *(const float4*)src;
      ar[2 * q + 1] = *(const float4*)(src + 4);
    }
  };
  auto writeA = [&](int buf) {
#pragma unroll
    for (int q = 0; q < 2; ++q) {
      int ci = tid + q * 512;
      uint2 a = pack_bf16x4(ar[2 * q]);
      uint2 b = pack_bf16x4(ar[2 * q + 1]);
      uint4 w; w.x = a.x; w.y = a.y; w.z = b.x; w.w = b.y;
      *(uint4*)&Asm[buf][ci * 8] = w;
    }
  };

  stageB(0, 0);
  loadA(0);
  int cur = 0;
  for (int kt = 0; kt < 12; ++kt) {
    writeA(cur);
    __syncthreads();
    if (kt < 11) { stageB(cur ^ 1, (kt + 1) * 64); loadA((kt + 1) * 64); }
    const char* Ab = (const char*)&Asm[cur][0];
    const char* Bb = (const char*)&Bsm[cur][0];
#pragma unroll
    for (int kk = 0; kk < 2; ++kk) {
      const int ks = (lg * 16 + kk * 64) ^ (l7 << 4);
      bf16x8 af[2], bfr[6];
#pragma unroll
      for (int mi = 0; mi < 2; ++mi)
        af[mi] = *(const bf16x8*)(Ab + (wm0 + mi * 16 + l15) * 128 + ks);
#pragma unroll
      for (int nj = 0; nj < 6; ++nj)
        bfr[nj] = *(const bf16x8*)(Bb + (wn0 + nj * 16 + l15) * 128 + ks);
#pragma unroll
      for (int mi = 0; mi < 2; ++mi)
#pragma unroll
        for (int nj = 0; nj < 6; ++nj)
          acc[mi][nj] = __builtin_amdgcn_mfma_f32_16x16x32_bf16(
              af[mi], bfr[nj], acc[mi][nj], 0, 0, 0);
    }
    cur ^= 1;
  }

#pragma unroll
  for (int nj = 0; nj < 6; ++nj) {
    const int n = wn0 + nj * 16 + l15;
    const float bi = bias[n];
#pragma unroll
    for (int mi = 0; mi < 2; ++mi) {
      const int mb = bm0 + wm0 + mi * 16 + lg * 4;
#pragma unroll
      for (int r = 0; r < 4; ++r)
        C[(size_t)(mb + r) * 192 + n] = __float2bfloat16(acc[mi][nj][r] + bi);
    }
  }
}

// ------------- full-K GEMM (K=192, BM=128): single-stage, 73.7KB LDS -------
// MODE 0: bf16 -> head-major qkv planes [(p*4+h)][m][48].
// MODE 1: + res, bf16 [m][N]. MODE 2: swapped mfma, fp32 permuted scatter + x.
template <int MODE>
__global__ __launch_bounds__(256) void gemm_fullk_kernel(
    const __hip_bfloat16* __restrict__ A, const __hip_bfloat16* __restrict__ W,
    const float* __restrict__ bias, const __hip_bfloat16* __restrict__ res,
    const float* __restrict__ xin, void* __restrict__ Cout, int N) {
  __shared__ __hip_bfloat16 Asm[3 * 128 * 64];  // 49152 B
  __shared__ __hip_bfloat16 Bsm[3 * 64 * 64];   // 24576 B

  const int tid = threadIdx.x;
  const int lane = tid & 63;
  const int wave = tid >> 6;

  const int gx = gridDim.x;
  const int lid = blockIdx.y * gx + blockIdx.x;
  const int seq = lid >> 3;
  const int bm0 = (((lid & 7) << 6) + seq / gx) << 7;     // m-panel XCD swizzle
  const int bn0 = (seq % gx) * 64;

  const int wm0 = (wave >> 1) * 64;
  const int wn0 = (wave & 1) * 32;
  const int l15 = lane & 15;
  const int l7 = lane & 7;
  const int lg = lane >> 4;

#pragma unroll
  for (int it = 0; it < 12; ++it) {
    int ci = tid + it * 256;
    int sec = ci >> 10, ri = ci & 1023;
    int r = ri >> 3, c = ri & 7;
    int sc = c ^ (r & 7);
    const __hip_bfloat16* src = A + (size_t)(bm0 + r) * 192 + sec * 64 + sc * 8;
    __builtin_amdgcn_global_load_lds((gv_t*)src, (lv_t*)&Asm[ci * 8], 16, 0, 0);
  }
#pragma unroll
  for (int it = 0; it < 6; ++it) {
    int ci = tid + it * 256;
    int sec = ci >> 9, ri = ci & 511;
    int r = ri >> 3, c = ri & 7;
    int sc = c ^ (r & 7);
    const __hip_bfloat16* src = W + (size_t)(bn0 + r) * 192 + sec * 64 + sc * 8;
    __builtin_amdgcn_global_load_lds((gv_t*)src, (lv_t*)&Bsm[ci * 8], 16, 0, 0);
  }
  __syncthreads();

  f32x4 acc[4][2] = {};
  const char* Ab = (const char*)Asm;
  const char* Bb = (const char*)Bsm;
#pragma unroll
  for (int kk = 0; kk < 6; ++kk) {
    const int sec = kk >> 1, k2 = kk & 1;
    const int ks = (lg * 16 + k2 * 64) ^ (l7 << 4);
    bf16x8 af[4], bfr[2];
#pragma unroll
    for (int mi = 0; mi < 4; ++mi)
      af[mi] = *(const bf16x8*)(Ab + sec * 16384 + (wm0 + mi * 16 + l15) * 128 + ks);
#pragma unroll
    for (int nj = 0; nj < 2; ++nj)
      bfr[nj] = *(const bf16x8*)(Bb + sec * 8192 + (wn0 + nj * 16 + l15) * 128 + ks);
#pragma unroll
    for (int mi = 0; mi < 4; ++mi)
#pragma unroll
      for (int nj = 0; nj < 2; ++nj) {
        if constexpr (MODE == 2)
          acc[mi][nj] = __builtin_amdgcn_mfma_f32_16x16x32_bf16(
              bfr[nj], af[mi], acc[mi][nj], 0, 0, 0);   // D[row=n][col=m]
        else
          acc[mi][nj] = __builtin_amdgcn_mfma_f32_16x16x32_bf16(
              af[mi], bfr[nj], acc[mi][nj], 0, 0, 0);   // D[row=m][col=n]
      }
  }

  if constexpr (MODE == 2) {
    float* Cf = (float*)Cout;
#pragma unroll
    for (int nj = 0; nj < 2; ++nj) {
      const int n0 = bn0 + wn0 + nj * 16 + lg * 4;
      const f32x4 bi4 = *(const f32x4*)(bias + n0);
#pragma unroll
      for (int mi = 0; mi < 4; ++mi) {
        const int m = bm0 + wm0 + mi * 16 + l15;   // col = lane&15 -> m
        const int b = m >> 10;
        const int ll = m & 1023;
        const f32x4 xv = *(const f32x4*)(xin + (size_t)((ll << 6) | b) * 768 + n0);
        const size_t ob = (((size_t)(b >> 4) * 768 + n0) * 16 + (b & 15)) * 1024 + ll;
#pragma unroll
        for (int r = 0; r < 4; ++r)
          Cf[ob + (size_t)r * 16384] = acc[mi][nj][r] + bi4[r] + xv[r];
      }
    }
  } else if constexpr (MODE == 0) {
    // head-major qkv planes: n -> (p = n/192, h = (n%192)/48, d = n%48)
    __hip_bfloat16* Cb = (__hip_bfloat16*)Cout;
#pragma unroll
    for (int nj = 0; nj < 2; ++nj) {
      const int n = bn0 + wn0 + nj * 16 + l15;
      const int p = n / 192;
      const int rem = n - p * 192;
      const int h = rem / 48;
      const int d = rem - h * 48;
      const size_t plane = (size_t)(p * 4 + h) * PLANE;
      const float bi = bias[n];
#pragma unroll
      for (int mi = 0; mi < 4; ++mi) {
        const int mb = bm0 + wm0 + mi * 16 + lg * 4;
#pragma unroll
        for (int r = 0; r < 4; ++r)
          Cb[plane + (size_t)(mb + r) * 48 + d] =
              __float2bfloat16(acc[mi][nj][r] + bi);
      }
    }
  } else {
    __hip_bfloat16* Cb = (__hip_bfloat16*)Cout;
#pragma unroll
    for (int nj = 0; nj < 2; ++nj) {
      const int n = bn0 + wn0 + nj * 16 + l15;
      const float bi = bias[n];
#pragma unroll
      for (int mi = 0; mi < 4; ++mi) {
        const int mb = bm0 + wm0 + mi * 16 + lg * 4;
        f32x4 v = acc[mi][nj];
#pragma unroll
        for (int r = 0; r < 4; ++r) {
          const int m = mb + r;
          float val = v[r] + bi + __bfloat162float(res[(size_t)m * N + n]);
          Cb[(size_t)m * N + n] = __float2bfloat16(val);
        }
      }
    }
  }
}

// all six weights in one launch; i is a global float4 index
__global__ __launch_bounds__(256) void cvt_weights_kernel(
    const float* __restrict__ s0, const float* __restrict__ s1,
    const float* __restrict__ s2, const float* __restrict__ s3,
    const float* __restrict__ s4, const float* __restrict__ s5,
    __hip_bfloat16* __restrict__ d0, __hip_bfloat16* __restrict__ d1,
    __hip_bfloat16* __restrict__ d2, __hip_bfloat16* __restrict__ d3,
    __hip_bfloat16* __restrict__ d4, __hip_bfloat16* __restrict__ d5) {
  int i = blockIdx.x * 256 + threadIdx.x;   // 0..116735
  const float* src; __hip_bfloat16* dst; int off;
  if      (i < 36864)  { src = s0; dst = d0; off = i; }
  else if (i < 39936)  { src = s1; dst = d1; off = i - 36864; }
  else if (i < 43008)  { src = s2; dst = d2; off = i - 39936; }
  else if (i < 70656)  { src = s3; dst = d3; off = i - 43008; }
  else if (i < 79872)  { src = s4; dst = d4; off = i - 70656; }
  else                 { src = s5; dst = d5; off = i - 79872; }
  ((uint2*)dst)[off] = pack_bf16x4(((const float4*)src)[off]);
}

// ------- Fused bottleneck: convA -> convB -> +res -> GeLU -> LN ------------
__global__ __launch_bounds__(256, 2) void bottleneck_kernel(
    const __hip_bfloat16* __restrict__ xs0,
    const __hip_bfloat16* __restrict__ wA, const float* __restrict__ bA,
    const __hip_bfloat16* __restrict__ wB, const float* __restrict__ bB,
    const float* __restrict__ ln_g, const float* __restrict__ ln_b,
    __hip_bfloat16* __restrict__ xs_sp, __hip_bfloat16* __restrict__ ln_sp) {
  __shared__ __hip_bfloat16 xt[3 * 64 * 64];    // 24 KB
  __shared__ __hip_bfloat16 wAs[3 * 64 * 64];   // 24 KB
  __shared__ __hip_bfloat16 wBs[192 * 64];      // 24 KB
  __shared__ __hip_bfloat16 a2[64 * 64];        // 8 KB (stats overlaid later)

  const int tid = threadIdx.x;
  const int lane = tid & 63;
  const int wave = tid >> 6;
  const int bm0 = blockIdx.x * 64;
  const int l15 = lane & 15;
  const int lg = lane >> 4;
  const int wm0 = (wave >> 1) * 32;

#pragma unroll
  for (int it = 0; it < 6; ++it) {
    int ci = tid + it * 256;
    int sec = ci >> 9, ri = ci & 511;
    int r = ri >> 3, c = ri & 7;
    int sc = c ^ (r & 7);
    const __hip_bfloat16* src = xs0 + (size_t)(bm0 + r) * 192 + sec * 64 + sc * 8;
    __builtin_amdgcn_global_load_lds((gv_t*)src, (lv_t*)&xt[ci * 8], 16, 0, 0);
  }
#pragma unroll
  for (int it = 0; it < 6; ++it) {
    int ci = tid + it * 256;
    int sec = ci >> 9, ri = ci & 511;
    int r = ri >> 3, c = ri & 7;
    int sc = c ^ (r & 7);
    const __hip_bfloat16* src = wA + (size_t)r * 192 + sec * 64 + sc * 8;
    __builtin_amdgcn_global_load_lds((gv_t*)src, (lv_t*)&wAs[ci * 8], 16, 0, 0);
  }
#pragma unroll
  for (int it = 0; it < 6; ++it) {
    int ci = tid + it * 256;
    int r = ci >> 3, c = ci & 7;
    int sc = c ^ (r & 7);
    const __hip_bfloat16* src = wB + (size_t)r * 64 + sc * 8;
    __builtin_amdgcn_global_load_lds((gv_t*)src, (lv_t*)&wBs[ci * 8], 16, 0, 0);
  }
  __syncthreads();

  // ---- pass 1: a = xs0 @ wA^T + bA ----
  {
    const int wn0 = (wave & 1) * 32;
    f32x4 acc1[2][2] = {};
    const char* Ab = (const char*)xt;
    const char* Bb = (const char*)wAs;
#pragma unroll
    for (int kk = 0; kk < 6; ++kk) {
      const int sec = kk >> 1, k2 = kk & 1;
      const int ks = (lg * 16 + k2 * 64) ^ ((l15 & 7) << 4);
      bf16x8 af[2], bfr[2];
#pragma unroll
      for (int mi = 0; mi < 2; ++mi)
        af[mi] = *(const bf16x8*)(Ab + sec * 8192 + (wm0 + mi * 16 + l15) * 128 + ks);
#pragma unroll
      for (int nj = 0; nj < 2; ++nj)
        bfr[nj] = *(const bf16x8*)(Bb + sec * 8192 + (wn0 + nj * 16 + l15) * 128 + ks);
#pragma unroll
      for (int mi = 0; mi < 2; ++mi)
#pragma unroll
        for (int nj = 0; nj < 2; ++nj)
          acc1[mi][nj] = __builtin_amdgcn_mfma_f32_16x16x32_bf16(
              af[mi], bfr[nj], acc1[mi][nj], 0, 0, 0);
    }
#pragma unroll
    for (int nj = 0; nj < 2; ++nj) {
      const int n = wn0 + nj * 16 + l15;
      const float bi = bA[n];
#pragma unroll
      for (int mi = 0; mi < 2; ++mi)
#pragma unroll
        for (int r = 0; r < 4; ++r) {
          const int row = wm0 + mi * 16 + lg * 4 + r;
          a2[row * 64 + (((n >> 3) ^ (row & 7)) << 3) + (n & 7)] =
              __float2bfloat16(acc1[mi][nj][r] + bi);
        }
    }
  }
  __syncthreads();

  // ---- pass 2: b = a @ wB^T ----
  const int wn0 = (wave & 1) * 96;
  f32x4 acc2[2][6] = {};
  {
    const char* Ab = (const char*)a2;
    const char* Bb = (const char*)wBs;
#pragma unroll
    for (int kk = 0; kk < 2; ++kk) {
      const int ks = (lg * 16 + kk * 64) ^ ((l15 & 7) << 4);
      bf16x8 af[2], bfr[6];
#pragma unroll
      for (int mi = 0; mi < 2; ++mi)
        af[mi] = *(const bf16x8*)(Ab + (wm0 + mi * 16 + l15) * 128 + ks);
#pragma unroll
      for (int nj = 0; nj < 6; ++nj)
        bfr[nj] = *(const bf16x8*)(Bb + (wn0 + nj * 16 + l15) * 128 + ks);
#pragma unroll
      for (int mi = 0; mi < 2; ++mi)
#pragma unroll
        for (int nj = 0; nj < 6; ++nj)
          acc2[mi][nj] = __builtin_amdgcn_mfma_f32_16x16x32_bf16(
              af[mi], bfr[nj], acc2[mi][nj], 0, 0, 0);
    }
  }
  __syncthreads();   // a2 dead; safe to overlay stats

  float* stats = (float*)a2;

#pragma unroll
  for (int nj = 0; nj < 6; ++nj) {
    const int n = wn0 + nj * 16 + l15;
    const float bi = bB[n];
    const int sec = n >> 6, n6 = n & 63;
#pragma unroll
    for (int mi = 0; mi < 2; ++mi)
#pragma unroll
      for (int r = 0; r < 4; ++r) {
        const int row = wm0 + mi * 16 + lg * 4 + r;
        const int ei = sec * 4096 + row * 64 + (((n6 >> 3) ^ (row & 7)) << 3) + (n6 & 7);
        float v = acc2[mi][nj][r] + bi + __bfloat162float(xt[ei]);
        float ge = 0.5f * v * (1.0f + erff(v * 0.70710678118654752f));
        acc2[mi][nj][r] = ge;
        xt[ei] = __float2bfloat16(ge);
      }
  }
#pragma unroll
  for (int mi = 0; mi < 2; ++mi)
#pragma unroll
    for (int r = 0; r < 4; ++r) {
      float s1 = 0.0f, s2 = 0.0f;
#pragma unroll
      for (int nj = 0; nj < 6; ++nj) {
        float v = acc2[mi][nj][r];
        s1 += v;
        s2 += v * v;
      }
#pragma unroll
      for (int off = 1; off < 16; off <<= 1) {
        s1 += __shfl_xor(s1, off);
        s2 += __shfl_xor(s2, off);
      }
      if (l15 == 0) {
        const int row = wm0 + mi * 16 + lg * 4 + r;
        stats[row * 4 + (wave & 1) * 2 + 0] = s1;
        stats[row * 4 + (wave & 1) * 2 + 1] = s2;
      }
    }
  __syncthreads();

#pragma unroll
  for (int it = 0; it < 6; ++it) {
    int ci = tid + it * 256;
    int row = ci / 24, gr = ci % 24;
    int sec = gr >> 3, g8i = gr & 7;
    bf16x8 g8 = *(const bf16x8*)&xt[sec * 4096 + row * 64 + ((g8i ^ (row & 7)) << 3)];
    float s1 = stats[row * 4 + 0] + stats[row * 4 + 2];
    float s2 = stats[row * 4 + 1] + stats[row * 4 + 3];
    float mean = s1 * (1.0f / 192.0f);
    float var = s2 * (1.0f / 192.0f) - mean * mean;
    float rstd = rsqrtf(var + 1e-5f);
    const int m_l = bm0 + row;
    const size_t dst = ((size_t)(((m_l & 63) << 10) | (m_l >> 6))) * 192 + gr * 8;
    bf16x8 lnv;
#pragma unroll
    for (int u = 0; u < 8; ++u) {
      float g = (float)g8[u];
      lnv[u] = (__bf16)((g - mean) * rstd * ln_g[gr * 8 + u] + ln_b[gr * 8 + u]);
    }
    *(bf16x8*)(xs_sp + dst) = g8;
    *(bf16x8*)(ln_sp + dst) = lnv;
  }
}

// ---------------- Neighborhood attention: all-LDS, plane sources -----------
// Block = one (16x16 pixel tile, head). 256 threads, 1 pixel/lane.
// LDS: q_s 256px x 6 granules (24.6KB) + kv_s 20x20 halo, 7-granule pad rows
// (45KB). Per-thread state: s[25] + pv[8]. Plane layout makes all staging
// contiguous (16-px row = 1536B run; halo row = 1.9KB run).
__global__ __launch_bounds__(256) void natten_kernel(
    const __hip_bfloat16* __restrict__ qkv, const float* __restrict__ rpb,
    __hip_bfloat16* __restrict__ o) {
  __shared__ __hip_bfloat16 kv_s[2816 * 8];   // 45056 B
  __shared__ __hip_bfloat16 q_s[1536 * 8];    // 24576 B

  const int tid = threadIdx.x;
  const int bid = blockIdx.x;      // 1024 = 64 img * 2*2 tiles * 4 heads
  const int head = bid & 3;
  const int tj = (bid >> 2) & 1;
  const int ti = (bid >> 3) & 1;
  const int b = bid >> 4;

  const int hs = ti * 12;
  const int ws = tj * 12;
  const int i = ti * 16 + (tid >> 4);
  const int j = tj * 16 + (tid & 15);
  const int pix = (b << 10) + (i << 5) + j;
  const int ih0 = min(max(i - 2, 0), 27);
  const int iw0 = min(max(j - 2, 0), 27);
  const int oi = ih0 - hs;
  const int oj = iw0 - ws;
  const int dbh = ih0 - i + 4;
  const int dbw = iw0 - j + 4;

  const __hip_bfloat16* Qp = qkv + (size_t)head * PLANE;
  const __hip_bfloat16* Kp = qkv + (size_t)(4 + head) * PLANE;
  const __hip_bfloat16* Vp = qkv + (size_t)(8 + head) * PLANE;

  // ---- stage Q tile: 1536 granules, contiguous 1536B per 16-px row ----
#pragma unroll
  for (int it = 0; it < 6; ++it) {
    int ci = tid + it * 256;
    int px = ci / 6, c = ci % 6;
    int pi = ti * 16 + (px >> 4), pj = tj * 16 + (px & 15);
    const __hip_bfloat16* src =
        Qp + (size_t)((b << 10) + (pi << 5) + pj) * 48 + c * 8;
    __builtin_amdgcn_global_load_lds((gv_t*)src, (lv_t*)&q_s[ci * 8], 16, 0, 0);
  }
  // ---- stage K halo: 2816 granules (c==6 pad reads next pixel, in-bounds) --
#pragma unroll
  for (int it = 0; it < 11; ++it) {
    int ci = tid + it * 256;
    int r = ci / 7, c = ci % 7;
    int hr = r / 20, wr = r % 20;
    const __hip_bfloat16* src =
        Kp + (size_t)((b << 10) + (hs + hr) * 32 + (ws + wr)) * 48 + c * 8;
    __builtin_amdgcn_global_load_lds((gv_t*)src, (lv_t*)&kv_s[ci * 8], 16, 0, 0);
  }

  // seed scores with rpb * sqrt(48)  (scale applied inside exp later)
  float s[25];
#pragma unroll
  for (int x = 0; x < 5; ++x)
#pragma unroll
    for (int y = 0; y < 5; ++y)
      s[x * 5 + y] = rpb[head * 81 + (dbh + x) * 9 + (dbw + y)] * 6.9282032302755092f;

  __syncthreads();                 // Q + K staged

  // ---- QK, t-outer ----
  const char* qb = (const char*)q_s + tid * 96;
  const char* kvb = (const char*)kv_s + (oi * 20 + oj) * 112;
#pragma unroll
  for (int t = 0; t < 6; ++t) {
    const bf16x8 qv = *(const bf16x8*)(qb + t * 16);
#pragma unroll
    for (int x = 0; x < 5; ++x) {
#pragma unroll
      for (int y = 0; y < 5; ++y) {
        const bf16x8 kv = *(const bf16x8*)(kvb + (x * 20 + y) * 112 + t * 16);
        float a = 0.0f;
#pragma unroll
        for (int u = 0; u < 8; ++u) a += (float)qv[u] * (float)kv[u];
        s[x * 5 + y] += a;
      }
    }
  }
  __syncthreads();                 // all waves done reading K

  // ---- stage V halo (same slots) ----
#pragma unroll
  for (int it = 0; it < 11; ++it) {
    int ci = tid + it * 256;
    int r = ci / 7, c = ci % 7;
    int hr = r / 20, wr = r % 20;
    const __hip_bfloat16* src =
        Vp + (size_t)((b << 10) + (hs + hr) * 32 + (ws + wr)) * 48 + c * 8;
    __builtin_amdgcn_global_load_lds((gv_t*)src, (lv_t*)&kv_s[ci * 8], 16, 0, 0);
  }

  // softmax (overlaps V staging); scale folded: e = exp((s-mx)*scale)
  float mx = s[0];
#pragma unroll
  for (int n = 1; n < 25; ++n) mx = fmaxf(mx, s[n]);
  float sum = 0.0f;
#pragma unroll
  for (int n = 0; n < 25; ++n) {
    s[n] = __expf((s[n] - mx) * 0.14433756729740643f);
    sum += s[n];
  }
  const float inv = 1.0f / sum;

  __syncthreads();                 // V staged

  // ---- PV (t-outer, pv[8] live) ----
  bf16x8* op = (bf16x8*)(o + (size_t)pix * 192 + head * 48);
#pragma unroll
  for (int t = 0; t < 6; ++t) {
    float pv[8] = {};
#pragma unroll
    for (int x = 0; x < 5; ++x) {
#pragma unroll
      for (int y = 0; y < 5; ++y) {
        const bf16x8 vv = *(const bf16x8*)(kvb + (x * 20 + y) * 112 + t * 16);
        const float w = s[x * 5 + y];
#pragma unroll
        for (int u = 0; u < 8; ++u) pv[u] += w * (float)vv[u];
      }
    }
    bf16x8 ov;
#pragma unroll
    for (int u = 0; u < 8; ++u) ov[u] = (__bf16)(pv[u] * inv);
    op[t] = ov;
  }
}

extern "C" void kernel_launch(void* const* d_in, const int* in_sizes, int n_in,
                              void* d_out, int out_size, void* d_ws, size_t ws_size,
                              hipStream_t stream) {
  const float* x       = (const float*)d_in[0];
  const float* fc1_w   = (const float*)d_in[1];
  const float* fc1_b   = (const float*)d_in[2];
  const float* convA_w = (const float*)d_in[3];
  const float* convA_b = (const float*)d_in[4];
  const float* convB_w = (const float*)d_in[5];
  const float* convB_b = (const float*)d_in[6];
  const float* ln_g    = (const float*)d_in[7];
  const float* ln_b    = (const float*)d_in[8];
  const float* qkv_w   = (const float*)d_in[9];
  const float* qkv_b   = (const float*)d_in[10];
  const float* rpb     = (const float*)d_in[11];
  const float* proj_w  = (const float*)d_in[12];
  const float* proj_b  = (const float*)d_in[13];
  const float* fc2_w   = (const float*)d_in[14];
  const float* fc2_b   = (const float*)d_in[15];
  float* out = (float*)d_out;

  char* W0 = (char*)d_ws;
  __hip_bfloat16* wfc1  = (__hip_bfloat16*)W0;
  __hip_bfloat16* wcvA  = wfc1 + 147456;
  __hip_bfloat16* wcvB  = wcvA + 12288;
  __hip_bfloat16* wqkv  = wcvB + 12288;
  __hip_bfloat16* wproj = wqkv + 110592;
  __hip_bfloat16* wfc2  = wproj + 36864;
  __hip_bfloat16* reg1  = wfc2 + 147456;                       // 37,748,736 elems
  __hip_bfloat16* xs0   = reg1;
  __hip_bfloat16* qkvb  = reg1;                                // alias after xs0 dead
  __hip_bfloat16* ybuf  = reg1;                                // alias after qkv dead
  __hip_bfloat16* xs_sp = reg1 + 37748736;                     // 12,582,912
  __hip_bfloat16* ln_sp = xs_sp + 12582912;                    // 12,582,912
  __hip_bfloat16* obuf  = ln_sp;                               // reuse after qkv GEMM

  // weights -> bf16 (one launch; 116736 float4s)
  cvt_weights_kernel<<<456, 256, 0, stream>>>(
      fc1_w, convA_w, convB_w, qkv_w, proj_w, fc2_w,
      wfc1, wcvA, wcvB, wqkv, wproj, wfc2);

  // 1. fc1 (fp32 A, in-register cvt)
  fc1_kernel<<<512, 512, 0, stream>>>(x, wfc1, fc1_b, xs0);
  // 2. fused bottleneck -> xs_sp, ln_sp
  bottleneck_kernel<<<1024, 256, 0, stream>>>(
      xs0, wcvA, convA_b, wcvB, convB_b, ln_g, ln_b, xs_sp, ln_sp);
  // 3. qkv -> head-major planes
  gemm_fullk_kernel<0><<<dim3(9, 512), 256, 0, stream>>>(
      ln_sp, wqkv, qkv_b, nullptr, nullptr, qkvb, 576);
  // 4. natten (all-LDS, plane sources)
  natten_kernel<<<1024, 256, 0, stream>>>(qkvb, rpb, obuf);
  // 5. proj + residual(xs_sp)
  gemm_fullk_kernel<1><<<dim3(3, 512), 256, 0, stream>>>(
      obuf, wproj, proj_b, xs_sp, nullptr, ybuf, 192);
  // 6. fc2 + residual(x) + permuted scatter
  gemm_fullk_kernel<2><<<dim3(12, 512), 256, 0, stream>>>(
      ybuf, wfc2, fc2_b, nullptr, x, (void*)out, 768);
}